// Round 5
// baseline (232.873 us; speedup 1.0000x reference)
//
#include <hip/hip_runtime.h>
#include <math.h>

#define N_BATCH 8
#define IN_CH   256
#define OUT_CH  256
#define T_LEN   2048
#define DKS     33
#define PAD     16
#define KC      16

// conv tiling
#define MT 32      // out-channels per block
#define TT 128     // time per block (4 waves x 32)
#define XS_STRIDE 40   // Xs row stride in bf16 elements (80B, 16B-aligned)

typedef __attribute__((ext_vector_type(8))) short bf16x8;
typedef __attribute__((ext_vector_type(4))) float f32x4;

__device__ __forceinline__ unsigned short f2bf(float f) {
    unsigned u = __builtin_bit_cast(unsigned, f);
    unsigned r = (u + 0x7FFFu + ((u >> 16) & 1u)) >> 16;   // RNE
    return (unsigned short)r;
}

// ---------------------------------------------------------------------------
// Kernel 1: construct dense conv kernel in bf16, fragment-ready layout:
//   element (o,i,d) lives at
//   ((g*8 + c)*33 + d)*2048 + a*512 + l*8 + j
//   where g=o>>6, a=(o>>4)&3, m=o&15, c=i>>5, i_local=i&31,
//         quad=i_local>>3, j=i_local&7, l=quad*16+m.
// GATHER formulation (no runtime-indexed array -> no scratch).
// Faithful reference semantics: frac from out-channel 0; second tap dropped
// when p1+1 == 33 (d-1 <= 31 never matches).
// ---------------------------------------------------------------------------
__global__ void build_kern(const float* __restrict__ weight,
                           const float* __restrict__ P,
                           unsigned short* __restrict__ kern_f) {
    int idx = blockIdx.x * blockDim.x + threadIdx.x;   // o*IN_CH + i
    if (idx >= OUT_CH * IN_CH) return;
    int o = idx / IN_CH;
    int i = idx % IN_CH;

    const float* Po = P      + (size_t)(o * IN_CH + i) * KC;
    const float* P0 = P      + (size_t)i * KC;           // out-channel 0
    const float* Wo = weight + (size_t)(o * IN_CH + i) * KC;

    int   p1[KC];
    float w1[KC], w2[KC];
#pragma unroll
    for (int k = 0; k < KC; ++k) {
        float pp = Po[k] + (float)(DKS / 2);
        float p0 = P0[k] + (float)(DKS / 2);
        float fr = p0 - floorf(p0);
        float w  = Wo[k];
        p1[k] = (int)floorf(pp);
        w1[k] = w * (1.0f - fr);
        w2[k] = w * fr;
    }

    int g  = o >> 6;
    int ai = (o >> 4) & 3;
    int m  = o & 15;
    int c  = i >> 5;
    int il = i & 31;
    int q  = il >> 3;
    int j  = il & 7;
    size_t base = ((size_t)(g * 8 + c) * 33) * 2048
                + (size_t)ai * 512 + (size_t)(q * 16 + m) * 8 + j;

#pragma unroll
    for (int d = 0; d < DKS; ++d) {
        float acc = 0.0f;
#pragma unroll
        for (int k = 0; k < KC; ++k) {
            acc += (p1[k] == d)     ? w1[k] : 0.0f;
            acc += (p1[k] == d - 1) ? w2[k] : 0.0f;
        }
        kern_f[base + (size_t)d * 2048] = f2bf(acc);
    }
}

// ---------------------------------------------------------------------------
// Kernel 2: implicit-GEMM conv with MFMA 16x16x32 bf16.
// Block: 256 thr = 4 waves. Block tile 32o x 128t; wave tile 32o x 32t.
// Grid (16,8,8) = (t-blocks, o-blocks, batch) -- r3 order, lowest FETCH_SIZE.
// Latency analysis (r4 post-mortem): VGPR=56 showed ZERO d-steps in flight
// per wave; per-SIMD stall ~200cy/step with all 4 waves waiting together.
// Fix: unroll the d-loop 3x (33 = 3*11, no tail) so the scheduler gets a
// straight-line body of 12 loads + 12 MFMAs to interleave with counted
// waits (m97 mechanism). Manual rotating buffers measurably hurt (r2);
// grid/cache-locality changes measurably null (r3/r4).
// ---------------------------------------------------------------------------
__global__ __launch_bounds__(256, 4) void dcls_conv(
    const float* __restrict__ x,
    const unsigned short* __restrict__ kern_f,
    const float* __restrict__ bias,
    float* __restrict__ out)
{
    __shared__ unsigned short Xs[(TT + 2 * PAD) * XS_STRIDE];  // 160*40*2B = 12.8KB

    const int t0    = blockIdx.x * TT;
    const int o0    = blockIdx.y * MT;
    const int batch = blockIdx.z;

    const int tid  = threadIdx.x;
    const int w    = tid >> 6;        // wave id 0..3
    const int l    = tid & 63;
    const int quad = l >> 4;
    const int lm   = l & 15;
    const int wt   = w * 32;          // wave's t base (local)

    f32x4 acc[2][2];
#pragma unroll
    for (int a = 0; a < 2; ++a)
#pragma unroll
        for (int b = 0; b < 2; ++b) acc[a][b] = (f32x4){0.f, 0.f, 0.f, 0.f};

    // kern base for this block's 32-o slice: g = by>>1, ai base = (by&1)*2
    const size_t kf_ai = (size_t)(blockIdx.y & 1) * 1024 + (size_t)l * 8;
    const int    kf_g  = blockIdx.y >> 1;

    for (int c = 0; c < 8; ++c) {
        __syncthreads();   // previous chunk's reads done before overwrite

        // ---- stage Xs: 32 i x 160 t, transposed, fp32 -> bf16 (RNE) ----
        const int i0 = c * 32;
#pragma unroll
        for (int it = 0; it < 10; ++it) {
            int idx = tid + it * 256;          // 0..2559
            int ip  = idx / 160;               // i-pair 0..15
            int t   = idx - ip * 160;          // 0..159
            int gg  = t0 - PAD + t;
            float v0 = 0.f, v1 = 0.f;
            if ((unsigned)gg < (unsigned)T_LEN) {
                const float* xb = x + ((size_t)(batch * IN_CH + i0 + ip * 2) * T_LEN) + gg;
                v0 = xb[0];
                v1 = xb[T_LEN];
            }
            unsigned pk = (unsigned)f2bf(v0) | ((unsigned)f2bf(v1) << 16);
            *(unsigned*)(&Xs[t * XS_STRIDE + ip * 2]) = pk;
        }
        __syncthreads();

        // ---- 33 barrier-free K-steps over d, 3x unrolled ----
        const unsigned short* kf = kern_f
            + ((size_t)(kf_g * 8 + c) * 33) * 2048 + kf_ai;

#pragma unroll 3
        for (int d = 0; d < DKS; ++d) {
            bf16x8 af[2];
#pragma unroll
            for (int a = 0; a < 2; ++a)
                af[a] = *(const bf16x8*)(kf + (size_t)d * 2048 + a * 512);
            bf16x8 bf[2];
#pragma unroll
            for (int b = 0; b < 2; ++b)
                bf[b] = *(const bf16x8*)(&Xs[(wt + b * 16 + lm + d) * XS_STRIDE + quad * 8]);
#pragma unroll
            for (int a = 0; a < 2; ++a)
#pragma unroll
                for (int b = 0; b < 2; ++b)
                    acc[a][b] = __builtin_amdgcn_mfma_f32_16x16x32_bf16(
                        af[a], bf[b], acc[a][b], 0, 0, 0);
        }
    }

    // ---- epilogue: bias + fp32 stores ----
#pragma unroll
    for (int a = 0; a < 2; ++a) {
#pragma unroll
        for (int r = 0; r < 4; ++r) {
            int o = o0 + a * 16 + quad * 4 + r;
            float bv = bias[o];
            float* orow = out + ((size_t)(batch * OUT_CH + o) * T_LEN) + t0 + wt + lm;
#pragma unroll
            for (int b = 0; b < 2; ++b)
                orow[b * 16] = acc[a][b][r] + bv;
        }
    }
}

extern "C" void kernel_launch(void* const* d_in, const int* in_sizes, int n_in,
                              void* d_out, int out_size, void* d_ws, size_t ws_size,
                              hipStream_t stream) {
    const float* x      = (const float*)d_in[0];
    const float* weight = (const float*)d_in[1];
    const float* P      = (const float*)d_in[2];
    const float* bias   = (const float*)d_in[3];
    float*       out    = (float*)d_out;
    unsigned short* kern_f = (unsigned short*)d_ws;   // 256*256*33 bf16 = 4.33MB

    hipLaunchKernelGGL(build_kern,
                       dim3((OUT_CH * IN_CH + 255) / 256), dim3(256), 0, stream,
                       weight, P, kern_f);

    dim3 grid(T_LEN / TT, OUT_CH / MT, N_BATCH);
    hipLaunchKernelGGL(dcls_conv, grid, dim3(256), 0, stream,
                       x, kern_f, bias, out);
}

// Round 6
// 188.845 us; speedup vs baseline: 1.2331x; 1.2331x over previous
//
#include <hip/hip_runtime.h>
#include <math.h>

#define N_BATCH 8
#define IN_CH   256
#define OUT_CH  256
#define T_LEN   2048
#define DKS     33
#define PAD     16
#define KC      16

// conv tiling: block = 4 waves, block tile 64o x 64t, FULL K per block.
// Each wave computes the WHOLE 64x64 tile over 2 of the 8 i-chunks
// (split-K across waves), with a private LDS x-slice -> barrier-free main
// loop. Final cross-wave reduce through LDS.
#define XS_STRIDE 40                       // bf16 elems/row (80B, 16B-aligned)
#define XS_ROWS   96                       // 64 t + 2*PAD
#define XS_BYTES  (XS_ROWS * XS_STRIDE * 2)   // 7680 B per wave
#define SLOT_BYTES (64 * 64 * 4)           // 16384 B f32 tile
#define SMEM_BYTES 32768                   // max(4*7680=30720, 2*16384)

typedef __attribute__((ext_vector_type(8))) short bf16x8;
typedef __attribute__((ext_vector_type(4))) float f32x4;

__device__ __forceinline__ unsigned short f2bf(float f) {
    unsigned u = __builtin_bit_cast(unsigned, f);
    unsigned r = (u + 0x7FFFu + ((u >> 16) & 1u)) >> 16;   // RNE
    return (unsigned short)r;
}

// ---------------------------------------------------------------------------
// Kernel 1: construct dense conv kernel in bf16, fragment-ready layout:
//   element (o,i,d) lives at
//   ((g*8 + c)*33 + d)*2048 + a*512 + l*8 + j
//   where g=o>>6, a=(o>>4)&3, m=o&15, c=i>>5, i_local=i&31,
//         quad=i_local>>3, j=i_local&7, l=quad*16+m.
// GATHER formulation (no runtime-indexed array -> no scratch).
// Faithful reference semantics: frac from out-channel 0; second tap dropped
// when p1+1 == 33 (d-1 <= 31 never matches).
// ---------------------------------------------------------------------------
__global__ void build_kern(const float* __restrict__ weight,
                           const float* __restrict__ P,
                           unsigned short* __restrict__ kern_f) {
    int idx = blockIdx.x * blockDim.x + threadIdx.x;   // o*IN_CH + i
    if (idx >= OUT_CH * IN_CH) return;
    int o = idx / IN_CH;
    int i = idx % IN_CH;

    const float* Po = P      + (size_t)(o * IN_CH + i) * KC;
    const float* P0 = P      + (size_t)i * KC;           // out-channel 0
    const float* Wo = weight + (size_t)(o * IN_CH + i) * KC;

    int   p1[KC];
    float w1[KC], w2[KC];
#pragma unroll
    for (int k = 0; k < KC; ++k) {
        float pp = Po[k] + (float)(DKS / 2);
        float p0 = P0[k] + (float)(DKS / 2);
        float fr = p0 - floorf(p0);
        float w  = Wo[k];
        p1[k] = (int)floorf(pp);
        w1[k] = w * (1.0f - fr);
        w2[k] = w * fr;
    }

    int g  = o >> 6;
    int ai = (o >> 4) & 3;
    int m  = o & 15;
    int c  = i >> 5;
    int il = i & 31;
    int q  = il >> 3;
    int j  = il & 7;
    size_t base = ((size_t)(g * 8 + c) * 33) * 2048
                + (size_t)ai * 512 + (size_t)(q * 16 + m) * 8 + j;

#pragma unroll
    for (int d = 0; d < DKS; ++d) {
        float acc = 0.0f;
#pragma unroll
        for (int k = 0; k < KC; ++k) {
            acc += (p1[k] == d)     ? w1[k] : 0.0f;
            acc += (p1[k] == d - 1) ? w2[k] : 0.0f;
        }
        kern_f[base + (size_t)d * 2048] = f2bf(acc);
    }
}

// ---------------------------------------------------------------------------
// Kernel 2: implicit-GEMM conv, wave tile 64o x 64t (16 MFMA per d-step).
// Rationale (r5 post-mortem): time across r1/r3/r4 was pinned by
// (MFMA-work/step) x (waves/SIMD) ~ 80cy << ~300cy load latency. This
// structure gives 16 MFMA/step x 4 waves/SIMD ~ 320cy of cover at the
// SAME occupancy, via split-K: wave w owns i-chunks {w, w+4}, stages them
// into a PRIVATE LDS slice (no __syncthreads in the main loop; same-wave
// ds ordering is pipeline-guaranteed), then a 3-phase LDS tree-reduce.
// Also halves per-CU operand traffic (8.4MB vs 17.3MB).
// ---------------------------------------------------------------------------
__global__ __launch_bounds__(256, 4) void dcls_conv(
    const float* __restrict__ x,
    const unsigned short* __restrict__ kern_f,
    const float* __restrict__ bias,
    float* __restrict__ out)
{
    __shared__ __align__(16) unsigned char smem[SMEM_BYTES];

    const int t0    = blockIdx.x * 64;
    const int g     = blockIdx.y;          // 64-o group 0..3
    const int o0    = g * 64;
    const int batch = blockIdx.z;

    const int tid  = threadIdx.x;
    const int w    = tid >> 6;        // wave id 0..3
    const int l    = tid & 63;
    const int quad = l >> 4;
    const int lm   = l & 15;

    unsigned short* Xw = (unsigned short*)(smem + w * XS_BYTES);  // private slice

    f32x4 acc[4][4];
#pragma unroll
    for (int a = 0; a < 4; ++a)
#pragma unroll
        for (int b = 0; b < 4; ++b) acc[a][b] = (f32x4){0.f, 0.f, 0.f, 0.f};

    const unsigned short* kfw = kern_f + (size_t)l * 8;

    for (int cc = 0; cc < 2; ++cc) {
        const int c  = w + cc * 4;        // this wave's i-chunk
        const int i0 = c * 32;

        // ---- stage private Xw: 96 t x 32 i, transposed, fp32 -> bf16 ----
#pragma unroll
        for (int it = 0; it < 24; ++it) {
            int idx = l + it * 64;         // 0..1535
            int ip  = idx / 96;            // i-pair 0..15
            int t   = idx - ip * 96;       // 0..95
            int gg  = t0 - PAD + t;
            float v0 = 0.f, v1 = 0.f;
            if ((unsigned)gg < (unsigned)T_LEN) {
                const float* xb = x + ((size_t)(batch * IN_CH + i0 + ip * 2) * T_LEN) + gg;
                v0 = xb[0];
                v1 = xb[T_LEN];
            }
            unsigned pk = (unsigned)f2bf(v0) | ((unsigned)f2bf(v1) << 16);
            *(unsigned*)(&Xw[t * XS_STRIDE + ip * 2]) = pk;
        }

        const unsigned short* kf = kfw + ((size_t)(g * 8 + c) * 33) * 2048;

        // ---- 33 barrier-free d-steps: 4 A + 4 B loads, 16 MFMA ----
        for (int d = 0; d < DKS; ++d) {
            bf16x8 af[4];
#pragma unroll
            for (int a = 0; a < 4; ++a)
                af[a] = *(const bf16x8*)(kf + (size_t)d * 2048 + a * 512);
            bf16x8 bf[4];
#pragma unroll
            for (int b = 0; b < 4; ++b)
                bf[b] = *(const bf16x8*)(&Xw[(b * 16 + lm + d) * XS_STRIDE + quad * 8]);
#pragma unroll
            for (int a = 0; a < 4; ++a)
#pragma unroll
                for (int b = 0; b < 4; ++b)
                    acc[a][b] = __builtin_amdgcn_mfma_f32_16x16x32_bf16(
                        af[a], bf[b], acc[a][b], 0, 0, 0);
        }
    }

    __syncthreads();   // all waves' compute done; LDS is repurposed below

    float* slot0 = (float*)(smem);
    float* slot1 = (float*)(smem + SLOT_BYTES);

    // C layout (verified r1/r3): o_local = a*16 + quad*4 + r, t_local = b*16 + lm
#define WRITE_SLOT(S)                                                         \
    {                                                                         \
        _Pragma("unroll")                                                     \
        for (int a = 0; a < 4; ++a)                                           \
            _Pragma("unroll")                                                 \
            for (int b = 0; b < 4; ++b)                                       \
                _Pragma("unroll")                                             \
                for (int r = 0; r < 4; ++r)                                   \
                    (S)[(a * 16 + quad * 4 + r) * 64 + b * 16 + lm] = acc[a][b][r]; \
    }
#define ADD_SLOT(S)                                                           \
    {                                                                         \
        _Pragma("unroll")                                                     \
        for (int a = 0; a < 4; ++a)                                           \
            _Pragma("unroll")                                                 \
            for (int b = 0; b < 4; ++b)                                       \
                _Pragma("unroll")                                             \
                for (int r = 0; r < 4; ++r)                                   \
                    acc[a][b][r] += (S)[(a * 16 + quad * 4 + r) * 64 + b * 16 + lm]; \
    }

    if (w == 2) WRITE_SLOT(slot0);
    if (w == 3) WRITE_SLOT(slot1);
    __syncthreads();
    if (w == 0) ADD_SLOT(slot0);      // w0 = chunks {0,4,2,6}
    if (w == 1) ADD_SLOT(slot1);      // w1 = chunks {1,5,3,7}
    __syncthreads();
    if (w == 1) WRITE_SLOT(slot0);
    __syncthreads();

    if (w == 0) {
        ADD_SLOT(slot0);              // full K sum
        // ---- epilogue: bias + fp32 stores ----
#pragma unroll
        for (int a = 0; a < 4; ++a) {
#pragma unroll
            for (int r = 0; r < 4; ++r) {
                int o = o0 + a * 16 + quad * 4 + r;
                float bv = bias[o];
                float* orow = out + ((size_t)(batch * OUT_CH + o) * T_LEN) + t0 + lm;
#pragma unroll
                for (int b = 0; b < 4; ++b)
                    orow[b * 16] = acc[a][b][r] + bv;
            }
        }
    }
#undef WRITE_SLOT
#undef ADD_SLOT
}

extern "C" void kernel_launch(void* const* d_in, const int* in_sizes, int n_in,
                              void* d_out, int out_size, void* d_ws, size_t ws_size,
                              hipStream_t stream) {
    const float* x      = (const float*)d_in[0];
    const float* weight = (const float*)d_in[1];
    const float* P      = (const float*)d_in[2];
    const float* bias   = (const float*)d_in[3];
    float*       out    = (float*)d_out;
    unsigned short* kern_f = (unsigned short*)d_ws;   // 256*256*33 bf16 = 4.33MB

    hipLaunchKernelGGL(build_kern,
                       dim3((OUT_CH * IN_CH + 255) / 256), dim3(256), 0, stream,
                       weight, P, kern_f);

    // block tile 64o x 64t, full K per block
    dim3 grid(T_LEN / 64, OUT_CH / 64, N_BATCH);
    hipLaunchKernelGGL(dcls_conv, grid, dim3(256), 0, stream,
                       x, kern_f, bias, out);
}

// Round 9
// 174.809 us; speedup vs baseline: 1.3322x; 1.0803x over previous
//
#include <hip/hip_runtime.h>
#include <math.h>

#define N_BATCH 8
#define IN_CH   256
#define OUT_CH  256
#define T_LEN   2048
#define DKS     33
#define PAD     16
#define KC      16

// conv tiling
#define MT 32      // out-channels per block
#define TT 128     // time per block (4 waves x 32)
#define XS_STRIDE 40   // Xs row stride in bf16 elements (80B, 16B-aligned)

typedef __attribute__((ext_vector_type(8))) short bf16x8;
typedef __attribute__((ext_vector_type(4))) float f32x4;

typedef const __attribute__((address_space(1))) unsigned int glb_uint;
typedef __attribute__((address_space(3))) unsigned int lds_uint;

__device__ __forceinline__ unsigned short f2bf(float f) {
    unsigned u = __builtin_bit_cast(unsigned, f);
    unsigned r = (u + 0x7FFFu + ((u >> 16) & 1u)) >> 16;   // RNE
    return (unsigned short)r;
}

// ---------------------------------------------------------------------------
// Kernel 1: construct dense conv kernel in bf16, fragment-ready layout:
//   element (o,i,d) lives at
//   ((g*8 + c)*33 + d)*2048 + a*512 + l*8 + j
//   where g=o>>6, a=(o>>4)&3, m=o&15, c=i>>5, i_local=i&31,
//         quad=i_local>>3, j=i_local&7, l=quad*16+m.
// GATHER formulation (no runtime-indexed array -> no scratch).
// Faithful reference semantics: frac from out-channel 0; second tap dropped
// when p1+1 == 33 (d-1 <= 31 never matches).
// ---------------------------------------------------------------------------
__global__ void build_kern(const float* __restrict__ weight,
                           const float* __restrict__ P,
                           unsigned short* __restrict__ kern_f) {
    int idx = blockIdx.x * blockDim.x + threadIdx.x;   // o*IN_CH + i
    if (idx >= OUT_CH * IN_CH) return;
    int o = idx / IN_CH;
    int i = idx % IN_CH;

    const float* Po = P      + (size_t)(o * IN_CH + i) * KC;
    const float* P0 = P      + (size_t)i * KC;           // out-channel 0
    const float* Wo = weight + (size_t)(o * IN_CH + i) * KC;

    int   p1[KC];
    float w1[KC], w2[KC];
#pragma unroll
    for (int k = 0; k < KC; ++k) {
        float pp = Po[k] + (float)(DKS / 2);
        float p0 = P0[k] + (float)(DKS / 2);
        float fr = p0 - floorf(p0);
        float w  = Wo[k];
        p1[k] = (int)floorf(pp);
        w1[k] = w * (1.0f - fr);
        w2[k] = w * fr;
    }

    int g  = o >> 6;
    int ai = (o >> 4) & 3;
    int m  = o & 15;
    int c  = i >> 5;
    int il = i & 31;
    int q  = il >> 3;
    int j  = il & 7;
    size_t base = ((size_t)(g * 8 + c) * 33) * 2048
                + (size_t)ai * 512 + (size_t)(q * 16 + m) * 8 + j;

#pragma unroll
    for (int d = 0; d < DKS; ++d) {
        float acc = 0.0f;
#pragma unroll
        for (int k = 0; k < KC; ++k) {
            acc += (p1[k] == d)     ? w1[k] : 0.0f;
            acc += (p1[k] == d - 1) ? w2[k] : 0.0f;
        }
        kern_f[base + (size_t)d * 2048] = f2bf(acc);
    }
}

// ---------------------------------------------------------------------------
// Kernel 2: implicit-GEMM conv with MFMA 16x16x32 bf16.
// Geometry = r3 (best measured): block 32o x 128t, 4 waves of 32o x 32t,
// grid (16,8,8), 4 blocks/CU.
// CHANGE (r6 post-mortem): conv was pinned ~117us across occupancy / ILP /
// cache variants -> the serialized resource is the per-wave global A-load
// path (8448 x 1KB L1 wave-instr per CU, full latency per step, VGPR=56
// proves zero prefetch). Fix = the one proven lever not yet applied
// (m97 Common-mistake #1): stage A via global_load_lds width=16 into
// double-buffered LDS, one d-PAIR per phase, single barrier per phase.
// Waves 0-1 issue the stage (wave-uniform LDS base + lane*16, linear);
// all 4 waves ds_read_b128 A conflict-free. Global A instr/CU drop 4x and
// the dependent load->MFMA chain becomes fire-and-forget.
// ---------------------------------------------------------------------------
__global__ __launch_bounds__(256, 4) void dcls_conv(
    const float* __restrict__ x,
    const unsigned short* __restrict__ kern_f,
    const float* __restrict__ bias,
    float* __restrict__ out)
{
    __shared__ unsigned short Xs[(TT + 2 * PAD) * XS_STRIDE];       // 12.8 KB
    __shared__ __align__(16) unsigned short Abuf[2][2][2][512];     // [buf][dd][a] 1KB rows = 8 KB

    const int t0    = blockIdx.x * TT;
    const int o0    = blockIdx.y * MT;
    const int batch = blockIdx.z;

    const int tid  = threadIdx.x;
    const int w    = tid >> 6;        // wave id 0..3
    const int l    = tid & 63;
    const int quad = l >> 4;
    const int lm   = l & 15;
    const int wt   = w * 32;          // wave's t base (local)

    f32x4 acc[2][2];
#pragma unroll
    for (int a = 0; a < 2; ++a)
#pragma unroll
        for (int b = 0; b < 2; ++b) acc[a][b] = (f32x4){0.f, 0.f, 0.f, 0.f};

    // this block's two A frag-rows within each d-slab: rows rb, rb+1 (of 4)
    const int rb   = (blockIdx.y & 1) * 2;
    const int kf_g = blockIdx.y >> 1;

    // stage A rows for d = DB..DB+CNT-1 of chunk base KB into Abuf[NB].
    // waves 0,1 issue; LDS dest is wave-uniform, HW adds lane*16.
#define STAGE_A(KB, DB, CNT, NB)                                              \
    do {                                                                      \
        if (w < 2) {                                                          \
            _Pragma("unroll")                                                 \
            for (int dd_ = 0; dd_ < (CNT); ++dd_) {                           \
                const unsigned short* s_ = kern_f + (KB)                      \
                    + (size_t)((DB) + dd_) * 2048 + (size_t)(rb + w) * 512    \
                    + (size_t)l * 8;                                          \
                __builtin_amdgcn_global_load_lds((glb_uint*)s_,               \
                    (lds_uint*)&Abuf[NB][dd_][w][0], 16, 0, 0);               \
            }                                                                 \
        }                                                                     \
    } while (0)

    for (int c = 0; c < 8; ++c) {
        const size_t kbase = ((size_t)(kf_g * 8 + c) * 33) * 2048;

        // prologue A-stage for d={0,1} (drains at the barrier below)
        STAGE_A(kbase, 0, 2, 0);

        // ---- stage Xs: 32 i x 160 t, transposed, fp32 -> bf16 (RNE) ----
        const int i0 = c * 32;
#pragma unroll
        for (int it = 0; it < 10; ++it) {
            int idx = tid + it * 256;          // 0..2559
            int ip  = idx / 160;               // i-pair 0..15
            int t   = idx - ip * 160;          // 0..159
            int gg  = t0 - PAD + t;
            float v0 = 0.f, v1 = 0.f;
            if ((unsigned)gg < (unsigned)T_LEN) {
                const float* xb = x + ((size_t)(batch * IN_CH + i0 + ip * 2) * T_LEN) + gg;
                v0 = xb[0];
                v1 = xb[T_LEN];
            }
            unsigned pk = (unsigned)f2bf(v0) | ((unsigned)f2bf(v1) << 16);
            *(unsigned*)(&Xs[t * XS_STRIDE + ip * 2]) = pk;
        }
        __syncthreads();   // Xs ready + A{0,1} landed

        // ---- 17 phases: 16 d-pairs + tail d=32; one barrier per phase ----
        for (int p = 0; p < 17; ++p) {
            const int cur = p & 1;

            if (p < 15) {
                STAGE_A(kbase, 2 * p + 2, 2, cur ^ 1);
            } else if (p == 15) {
                STAGE_A(kbase, 32, 1, cur ^ 1);
            }

            const int ndd = (p == 16) ? 1 : 2;
            for (int dd = 0; dd < ndd; ++dd) {
                const int d = (p == 16) ? 32 : 2 * p + dd;
                bf16x8 af[2];
#pragma unroll
                for (int a = 0; a < 2; ++a)
                    af[a] = *(const bf16x8*)(&Abuf[cur][dd][a][(size_t)l * 8]);
                bf16x8 bf[2];
#pragma unroll
                for (int b = 0; b < 2; ++b)
                    bf[b] = *(const bf16x8*)(&Xs[(wt + b * 16 + lm + d) * XS_STRIDE + quad * 8]);
#pragma unroll
                for (int a = 0; a < 2; ++a)
#pragma unroll
                    for (int b = 0; b < 2; ++b)
                        acc[a][b] = __builtin_amdgcn_mfma_f32_16x16x32_bf16(
                            af[a], bf[b], acc[a][b], 0, 0, 0);
            }
            __syncthreads();   // next buf staged (vmcnt drained) + cur free
        }
    }
#undef STAGE_A

    // ---- epilogue: bias + fp32 stores ----
#pragma unroll
    for (int a = 0; a < 2; ++a) {
#pragma unroll
        for (int r = 0; r < 4; ++r) {
            int o = o0 + a * 16 + quad * 4 + r;
            float bv = bias[o];
            float* orow = out + ((size_t)(batch * OUT_CH + o) * T_LEN) + t0 + wt + lm;
#pragma unroll
            for (int b = 0; b < 2; ++b)
                orow[b * 16] = acc[a][b][r] + bv;
        }
    }
}

extern "C" void kernel_launch(void* const* d_in, const int* in_sizes, int n_in,
                              void* d_out, int out_size, void* d_ws, size_t ws_size,
                              hipStream_t stream) {
    const float* x      = (const float*)d_in[0];
    const float* weight = (const float*)d_in[1];
    const float* P      = (const float*)d_in[2];
    const float* bias   = (const float*)d_in[3];
    float*       out    = (float*)d_out;
    unsigned short* kern_f = (unsigned short*)d_ws;   // 256*256*33 bf16 = 4.33MB

    hipLaunchKernelGGL(build_kern,
                       dim3((OUT_CH * IN_CH + 255) / 256), dim3(256), 0, stream,
                       weight, P, kern_f);

    dim3 grid(T_LEN / TT, OUT_CH / MT, N_BATCH);
    hipLaunchKernelGGL(dcls_conv, grid, dim3(256), 0, stream,
                       x, kern_f, bias, out);
}

// Round 11
// 161.848 us; speedup vs baseline: 1.4388x; 1.0801x over previous
//
#include <hip/hip_runtime.h>
#include <math.h>

#define N_BATCH 8
#define IN_CH   256
#define OUT_CH  256
#define T_LEN   2048
#define DKS     33
#define PAD     16
#define KC      16

// conv tiling
#define MT 32      // out-channels per block
#define TT 128     // time per block (4 waves x 32)
#define XS_STRIDE 40   // Xs row stride in bf16 elements (80B, 16B-aligned)

typedef __attribute__((ext_vector_type(8))) short bf16x8;
typedef __attribute__((ext_vector_type(4))) float f32x4;

typedef const __attribute__((address_space(1))) unsigned int glb_uint;
typedef __attribute__((address_space(3))) unsigned int lds_uint;

__device__ __forceinline__ unsigned short f2bf(float f) {
    unsigned u = __builtin_bit_cast(unsigned, f);
    unsigned r = (u + 0x7FFFu + ((u >> 16) & 1u)) >> 16;   // RNE
    return (unsigned short)r;
}

// ---------------------------------------------------------------------------
// Kernel 1: construct dense conv kernel in bf16, fragment-ready layout:
//   element (o,i,d) lives at
//   ((g*8 + c)*33 + d)*2048 + a*512 + l*8 + j
//   where g=o>>6, a=(o>>4)&3, m=o&15, c=i>>5, i_local=i&31,
//         quad=i_local>>3, j=i_local&7, l=quad*16+m.
// GATHER formulation (no runtime-indexed array -> no scratch).
// Faithful reference semantics: frac from out-channel 0; second tap dropped
// when p1+1 == 33 (d-1 <= 31 never matches).
// ---------------------------------------------------------------------------
__global__ void build_kern(const float* __restrict__ weight,
                           const float* __restrict__ P,
                           unsigned short* __restrict__ kern_f) {
    int idx = blockIdx.x * blockDim.x + threadIdx.x;   // o*IN_CH + i
    if (idx >= OUT_CH * IN_CH) return;
    int o = idx / IN_CH;
    int i = idx % IN_CH;

    const float* Po = P      + (size_t)(o * IN_CH + i) * KC;
    const float* P0 = P      + (size_t)i * KC;           // out-channel 0
    const float* Wo = weight + (size_t)(o * IN_CH + i) * KC;

    int   p1[KC];
    float w1[KC], w2[KC];
#pragma unroll
    for (int k = 0; k < KC; ++k) {
        float pp = Po[k] + (float)(DKS / 2);
        float p0 = P0[k] + (float)(DKS / 2);
        float fr = p0 - floorf(p0);
        float w  = Wo[k];
        p1[k] = (int)floorf(pp);
        w1[k] = w * (1.0f - fr);
        w2[k] = w * fr;
    }

    int g  = o >> 6;
    int ai = (o >> 4) & 3;
    int m  = o & 15;
    int c  = i >> 5;
    int il = i & 31;
    int q  = il >> 3;
    int j  = il & 7;
    size_t base = ((size_t)(g * 8 + c) * 33) * 2048
                + (size_t)ai * 512 + (size_t)(q * 16 + m) * 8 + j;

#pragma unroll
    for (int d = 0; d < DKS; ++d) {
        float acc = 0.0f;
#pragma unroll
        for (int k = 0; k < KC; ++k) {
            acc += (p1[k] == d)     ? w1[k] : 0.0f;
            acc += (p1[k] == d - 1) ? w2[k] : 0.0f;
        }
        kern_f[base + (size_t)d * 2048] = f2bf(acc);
    }
}

// ---------------------------------------------------------------------------
// Kernel 2: implicit-GEMM conv with MFMA 16x16x32 bf16.
// Geometry = r3: block 32o x 128t, 4 waves of 32o x 32t, grid (16,8,8).
// Counted-vmcnt pipeline (T4/m218), sync discipline per m201 template:
//   STAGE(p+2) ; VMW(2) ; BAR() ; PHASE(p)
// - ALL 4 waves stage (1 x 1KB global_load_lds each) so every wave's vmcnt
//   tracks its own loads (r10 bug: waves 2/3 had vmcnt==0 -> raced).
// - VMW BEFORE the barrier: barrier-arrival implies per-wave completion of
//   phase p's loads -> all waves may read the full 4KB buffer after BAR.
// - VMW(2) steady state: the two newer stages stay in flight (never 0).
// - Buffer distance 4: buf (p&3) rewritten at iter p+2, which is issued
//   after BAR(p+1), which is after all waves finished reading it (their
//   ds_reads complete before their MFMAs consume them, within PHASE(p)).
// d=32 tail outside the phase loop. T5 setprio around MFMA cluster.
// ---------------------------------------------------------------------------
__global__ __launch_bounds__(256, 4) void dcls_conv(
    const float* __restrict__ x,
    const unsigned short* __restrict__ kern_f,
    const float* __restrict__ bias,
    float* __restrict__ out)
{
    __shared__ unsigned short Xs[(TT + 2 * PAD) * XS_STRIDE];       // 12.8 KB
    __shared__ __align__(16) unsigned short Abuf[4][2][2][512];     // 16 KB

    const int t0    = blockIdx.x * TT;
    const int o0    = blockIdx.y * MT;
    const int batch = blockIdx.z;

    const int tid  = threadIdx.x;
    const int w    = tid >> 6;        // wave id 0..3
    const int l    = tid & 63;
    const int quad = l >> 4;
    const int lm   = l & 15;
    const int wt   = w * 32;          // wave's t base (local)

    f32x4 acc[2][2];
#pragma unroll
    for (int a = 0; a < 2; ++a)
#pragma unroll
        for (int b = 0; b < 2; ++b) acc[a][b] = (f32x4){0.f, 0.f, 0.f, 0.f};

    // this block's two A frag-rows within each d-slab: rows rb, rb+1 (of 4)
    const int rb   = (blockIdx.y & 1) * 2;
    const int kf_g = blockIdx.y >> 1;

    // wave's share of each 4KB d-pair slab: d-pair element w>>1, a-row w&1
    const int sdd = w >> 1;
    const int sa  = w & 1;

#define VMW(N) asm volatile("s_waitcnt vmcnt(" #N ")" ::: "memory")
#define BAR()  asm volatile("s_barrier" ::: "memory")

    // stage A d-pair {DB, DB+1} into Abuf[NB]; 1 x 1KB load per wave.
#define STAGE_A(KB, DB, NB)                                                   \
    do {                                                                      \
        const unsigned short* s_ = kern_f + (KB)                              \
            + (size_t)((DB) + sdd) * 2048 + (size_t)(rb + sa) * 512           \
            + (size_t)l * 8;                                                  \
        __builtin_amdgcn_global_load_lds((glb_uint*)s_,                       \
            (lds_uint*)&Abuf[NB][sdd][sa][0], 16, 0, 0);                      \
    } while (0)

    // one phase: read A d-pair {D0,D0+1} from Abuf[NB], B from Xs, 8 MFMA
#define PHASE_BODY(NB, D0)                                                    \
    do {                                                                      \
        bf16x8 afr[2][2], bfr[2][2];                                          \
        _Pragma("unroll")                                                     \
        for (int dd = 0; dd < 2; ++dd) {                                      \
            _Pragma("unroll")                                                 \
            for (int a = 0; a < 2; ++a)                                       \
                afr[dd][a] = *(const bf16x8*)(&Abuf[NB][dd][a][(size_t)l * 8]); \
            _Pragma("unroll")                                                 \
            for (int b = 0; b < 2; ++b)                                       \
                bfr[dd][b] = *(const bf16x8*)(&Xs[(wt + b * 16 + lm + (D0) + dd) * XS_STRIDE + quad * 8]); \
        }                                                                     \
        __builtin_amdgcn_s_setprio(1);                                        \
        _Pragma("unroll")                                                     \
        for (int dd = 0; dd < 2; ++dd)                                        \
            _Pragma("unroll")                                                 \
            for (int a = 0; a < 2; ++a)                                       \
                _Pragma("unroll")                                             \
                for (int b = 0; b < 2; ++b)                                   \
                    acc[a][b] = __builtin_amdgcn_mfma_f32_16x16x32_bf16(      \
                        afr[dd][a], bfr[dd][b], acc[a][b], 0, 0, 0);          \
        __builtin_amdgcn_s_setprio(0);                                        \
    } while (0)

    for (int c = 0; c < 8; ++c) {
        const size_t kbase = ((size_t)(kf_g * 8 + c) * 33) * 2048;

        __syncthreads();   // previous chunk's Xs/Abuf reads done

        // prologue: 2-deep A prefetch for phases 0,1 (d 0..3)
        STAGE_A(kbase, 0, 0);
        STAGE_A(kbase, 2, 1);

        // ---- stage Xs: 32 i x 160 t, transposed, fp32 -> bf16 (RNE) ----
        const int i0 = c * 32;
#pragma unroll
        for (int it = 0; it < 10; ++it) {
            int idx = tid + it * 256;          // 0..2559
            int ip  = idx / 160;               // i-pair 0..15
            int t   = idx - ip * 160;          // 0..159
            int gg  = t0 - PAD + t;
            float v0 = 0.f, v1 = 0.f;
            if ((unsigned)gg < (unsigned)T_LEN) {
                const float* xb = x + ((size_t)(batch * IN_CH + i0 + ip * 2) * T_LEN) + gg;
                v0 = xb[0];
                v1 = xb[T_LEN];
            }
            unsigned pk = (unsigned)f2bf(v0) | ((unsigned)f2bf(v1) << 16);
            *(unsigned*)(&Xs[t * XS_STRIDE + ip * 2]) = pk;
        }
        __syncthreads();   // Xs ready; prologue A-stages drained (vmcnt 0)

        // ---- 16 d-pair phases, counted-vmcnt pipeline (never drain 0) ----
        for (int p = 0; p < 14; ++p) {
            STAGE_A(kbase, 2 * p + 4, (p + 2) & 3);   // stage phase p+2
            VMW(2);    // this wave's phase-p load landed (2 newer in flight)
            BAR();     // all waves arrived => full buf[p&3] is resident
            PHASE_BODY(p & 3, 2 * p);
        }
        VMW(1); BAR(); PHASE_BODY(2, 28);   // p=14
        VMW(0); BAR(); PHASE_BODY(3, 30);   // p=15

        // ---- d=32 tail: A per-wave from global (L2-hot), once per chunk ----
        {
            bf16x8 af[2];
#pragma unroll
            for (int a = 0; a < 2; ++a)
                af[a] = *(const bf16x8*)(kern_f + kbase + (size_t)32 * 2048
                                         + (size_t)(rb + a) * 512 + (size_t)l * 8);
            bf16x8 bf[2];
#pragma unroll
            for (int b = 0; b < 2; ++b)
                bf[b] = *(const bf16x8*)(&Xs[(wt + b * 16 + lm + 32) * XS_STRIDE + quad * 8]);
#pragma unroll
            for (int a = 0; a < 2; ++a)
#pragma unroll
                for (int b = 0; b < 2; ++b)
                    acc[a][b] = __builtin_amdgcn_mfma_f32_16x16x32_bf16(
                        af[a], bf[b], acc[a][b], 0, 0, 0);
        }
    }
#undef STAGE_A
#undef PHASE_BODY
#undef VMW
#undef BAR

    // ---- epilogue: bias + fp32 stores ----
#pragma unroll
    for (int a = 0; a < 2; ++a) {
#pragma unroll
        for (int r = 0; r < 4; ++r) {
            int o = o0 + a * 16 + quad * 4 + r;
            float bv = bias[o];
            float* orow = out + ((size_t)(batch * OUT_CH + o) * T_LEN) + t0 + wt + lm;
#pragma unroll
            for (int b = 0; b < 2; ++b)
                orow[b * 16] = acc[a][b][r] + bv;
        }
    }
}

extern "C" void kernel_launch(void* const* d_in, const int* in_sizes, int n_in,
                              void* d_out, int out_size, void* d_ws, size_t ws_size,
                              hipStream_t stream) {
    const float* x      = (const float*)d_in[0];
    const float* weight = (const float*)d_in[1];
    const float* P      = (const float*)d_in[2];
    const float* bias   = (const float*)d_in[3];
    float*       out    = (float*)d_out;
    unsigned short* kern_f = (unsigned short*)d_ws;   // 256*256*33 bf16 = 4.33MB

    hipLaunchKernelGGL(build_kern,
                       dim3((OUT_CH * IN_CH + 255) / 256), dim3(256), 0, stream,
                       weight, P, kern_f);

    dim3 grid(T_LEN / TT, OUT_CH / MT, N_BATCH);
    hipLaunchKernelGGL(dcls_conv, grid, dim3(256), 0, stream,
                       x, kern_f, bias, out);
}